// Round 2
// baseline (10868.224 us; speedup 1.0000x reference)
//
#include <hip/hip_runtime.h>
#include <hip/hip_bf16.h>

#define SEQ  2048
#define EDIM 300
#define HDIM 150
#define FH   600   // 4*H
#define DDIM 300   // 2*H
#define DE   600   // D + E

__device__ __forceinline__ float frcp_(float x) { return __builtin_amdgcn_rcpf(x); }
__device__ __forceinline__ float sigm_(float x) { return frcp_(1.f + __expf(-x)); }
__device__ __forceinline__ float tanh_(float x) { return 1.f - 2.f * frcp_(1.f + __expf(2.f * x)); }

__device__ __forceinline__ float wave_red(float v) {
#pragma unroll
    for (int off = 32; off; off >>= 1) v += __shfl_down(v, off, 64);
    return v;
}

// ---------------------------------------------------------------------------
// xp = gather(emb, sentence) @ W{f,b} + b{f,b}   -> [SEQ,600] per direction
// ---------------------------------------------------------------------------
__global__ __launch_bounds__(256) void k_xp(
    const int* __restrict__ sent, const float* __restrict__ emb,
    const float* __restrict__ Wf, const float* __restrict__ bfv,
    const float* __restrict__ Wb, const float* __restrict__ bbv,
    float* __restrict__ xpf, float* __restrict__ xpb)
{
    __shared__ float xs[16][EDIM];
    const int tid = threadIdx.x;
    const int t0  = blockIdx.x * 16;

    for (int i = tid; i < 16 * EDIM; i += 256) {
        int r = i / EDIM, e = i - r * EDIM;
        int row = sent[t0 + r];
        xs[r][e] = emb[(size_t)row * EDIM + e];
    }
    __syncthreads();

    float acc[5][16];
#pragma unroll
    for (int c = 0; c < 5; c++)
#pragma unroll
        for (int r = 0; r < 16; r++) acc[c][r] = 0.f;

    const float* wp[5];
    bool val[5];
#pragma unroll
    for (int c = 0; c < 5; c++) {
        int j = tid + 256 * c;
        val[c] = (j < 1200);
        wp[c] = (j < 600) ? (Wf + j) : (Wb + (j < 1200 ? j - 600 : 0));
    }

    for (int e = 0; e < EDIM; e++) {
        float xr[16];
#pragma unroll
        for (int r = 0; r < 16; r++) xr[r] = xs[r][e];
#pragma unroll
        for (int c = 0; c < 5; c++) {
            if (val[c]) {
                float w = wp[c][(size_t)e * FH];
#pragma unroll
                for (int r = 0; r < 16; r++) acc[c][r] += xr[r] * w;
            }
        }
    }

#pragma unroll
    for (int c = 0; c < 5; c++) {
        int j = tid + 256 * c;
        if (j < 1200) {
            bool isF = (j < 600);
            int jj = isF ? j : j - 600;
            float bias = isF ? bfv[jj] : bbv[jj];
            float* dst = isF ? xpf : xpb;
#pragma unroll
            for (int r = 0; r < 16; r++)
                dst[(size_t)(t0 + r) * FH + jj] = acc[c][r] + bias;
        }
    }
}

// ---------------------------------------------------------------------------
// Serial LSTM recurrence. Block 0 = forward, block 1 = backward.
// U column held per-thread: 152 fp32 VGPRs (150 + 2 zero pad for float4 h-reads).
// __launch_bounds__(640,3): 10 waves, worst SIMD 3 waves -> cap ~170 VGPRs.
// ---------------------------------------------------------------------------
__global__ __launch_bounds__(640, 3) void k_lstm(
    const float* __restrict__ Uf, const float* __restrict__ Ub,
    const float* __restrict__ xpf, const float* __restrict__ xpb,
    float* __restrict__ hs)
{
    const int dir = blockIdx.x;
    const float* U  = dir ? Ub : Uf;
    const float* xp = dir ? xpb : xpf;

    __shared__ __align__(16) float hsh[HDIM + 2];
    __shared__ float zsh[FH];
    const int j = threadIdx.x;

    float Ucol[152];
    if (j < FH) {
#pragma unroll
        for (int k = 0; k < 152; k++)
            Ucol[k] = (k < HDIM) ? U[(size_t)k * FH + j] : 0.f;
    }
    if (j < HDIM + 2) hsh[j] = 0.f;
    float c = 0.f;
    __syncthreads();

    float xq = (j < FH) ? xp[(size_t)(dir ? SEQ - 1 : 0) * FH + j] : 0.f;

    for (int step = 0; step < SEQ; step++) {
        const int t  = dir ? (SEQ - 1 - step) : step;
        const int tn = dir ? (SEQ - 2 - step) : (step + 1);
        if (j < FH) {
            float z0 = xq;
            if (step + 1 < SEQ) xq = xp[(size_t)tn * FH + j];  // prefetch next step
            const float4* h4 = (const float4*)hsh;
            float s0 = z0, s1 = 0.f, s2 = 0.f, s3 = 0.f;
#pragma unroll
            for (int k = 0; k < 38; k++) {
                float4 hv = h4[k];          // wave-uniform broadcast read
                s0 += hv.x * Ucol[4 * k + 0];
                s1 += hv.y * Ucol[4 * k + 1];
                s2 += hv.z * Ucol[4 * k + 2];
                s3 += hv.w * Ucol[4 * k + 3];
            }
            zsh[j] = (s0 + s1) + (s2 + s3);
        }
        __syncthreads();
        if (j < HDIM) {
            float zi = zsh[j], zf = zsh[HDIM + j], zg = zsh[2 * HDIM + j], zo = zsh[3 * HDIM + j];
            float ig = sigm_(zi), fg = sigm_(zf), og = sigm_(zo);
            float g  = tanh_(zg);
            c = fg * c + ig * g;
            float hn = og * tanh_(c);
            hsh[j] = hn;
            hs[(size_t)t * DDIM + dir * HDIM + j] = hn;
        }
        __syncthreads();
    }
}

// ---------------------------------------------------------------------------
// out_e = hs @ W_pe + b_pe ; out_s = hs @ W_ps + b_ps
// ---------------------------------------------------------------------------
__global__ __launch_bounds__(256) void k_out(
    const float* __restrict__ hs,
    const float* __restrict__ Wpe, const float* __restrict__ bpe,
    const float* __restrict__ Wps, const float* __restrict__ bps,
    float* __restrict__ oe, float* __restrict__ os)
{
    __shared__ float xs[16 * DDIM];
    const int tid = threadIdx.x;
    const int t0  = blockIdx.x * 16;

    for (int i = tid; i < 16 * DDIM; i += 256) xs[i] = hs[(size_t)t0 * DDIM + i];
    __syncthreads();

    float acc[3][16];
#pragma unroll
    for (int c = 0; c < 3; c++)
#pragma unroll
        for (int r = 0; r < 16; r++) acc[c][r] = 0.f;

    const float* wp[3];
    bool val[3];
#pragma unroll
    for (int c = 0; c < 3; c++) {
        int j = tid + 256 * c;
        val[c] = (j < 600);
        wp[c] = (j < 300) ? (Wpe + j) : (Wps + (j < 600 ? j - 300 : 0));
    }

    for (int e = 0; e < DDIM; e++) {
        float xr[16];
#pragma unroll
        for (int r = 0; r < 16; r++) xr[r] = xs[r * DDIM + e];
#pragma unroll
        for (int c = 0; c < 3; c++) {
            if (val[c]) {
                float w = wp[c][(size_t)e * DDIM];
#pragma unroll
                for (int r = 0; r < 16; r++) acc[c][r] += xr[r] * w;
            }
        }
    }

#pragma unroll
    for (int c = 0; c < 3; c++) {
        int j = tid + 256 * c;
        if (j < 600) {
            bool isE = (j < 300);
            int jj = isE ? j : j - 300;
            float bias = isE ? bpe[jj] : bps[jj];
            float* dst = isE ? oe : os;
#pragma unroll
            for (int r = 0; r < 16; r++)
                dst[(size_t)(t0 + r) * DDIM + jj] = acc[c][r] + bias;
        }
    }
}

// ---------------------------------------------------------------------------
// Primary + secondary attention, accumulate H_HAT / H_BAR (8 sentences/block)
// ---------------------------------------------------------------------------
__global__ __launch_bounds__(256) void k_attn(
    const int* __restrict__ sent, const int* __restrict__ syn,
    const float* __restrict__ emb,
    const float* __restrict__ hs, const float* __restrict__ oeA, const float* __restrict__ osA,
    const float* __restrict__ w_se, const float* __restrict__ b_se,
    const float* __restrict__ w_ss, const float* __restrict__ b_ss,
    float* __restrict__ accHat, float* __restrict__ accBar)
{
    __shared__ float Loe[DDIM], Los[DDIM], Lh[DDIM];
    __shared__ float Lsyn[4][EDIM];
    __shared__ float Lme[EDIM], Lms[EDIM];
    __shared__ float Lred[4][8];
    __shared__ float Latt[8];
    __shared__ float Lco[2];

    const int tid = threadIdx.x;
    const int wv = tid >> 6, lane = tid & 63;
    float aH[3] = {0.f, 0.f, 0.f}, aB[3] = {0.f, 0.f, 0.f};

    for (int i8 = 0; i8 < 8; i8++) {
        const int s = blockIdx.x * 8 + i8;
        for (int i = tid; i < DDIM; i += 256) {
            Loe[i] = oeA[(size_t)s * DDIM + i];
            Los[i] = osA[(size_t)s * DDIM + i];
            Lh[i]  = hs [(size_t)s * DDIM + i];
        }
        const int sid = sent[s];
        for (int i = tid; i < 4 * EDIM; i += 256) {
            int k4 = i / EDIM, e = i - k4 * EDIM;
            int row = syn[sid * 4 + k4];
            Lsyn[k4][e] = emb[(size_t)row * EDIM + e];
        }
        __syncthreads();

        float p[8];
#pragma unroll
        for (int q = 0; q < 8; q++) p[q] = 0.f;
        for (int d = tid; d < EDIM; d += 256) {
            float voe = Loe[d], vos = Los[d];
#pragma unroll
            for (int k4 = 0; k4 < 4; k4++) {
                float sv = Lsyn[k4][d];
                p[k4]     += voe * sv;
                p[4 + k4] += vos * sv;
            }
        }
#pragma unroll
        for (int q = 0; q < 8; q++) {
            float r = wave_red(p[q]);
            if (lane == 0) Lred[wv][q] = r;
        }
        __syncthreads();
        if (tid < 8)
            Latt[tid] = __expf(Lred[0][tid] + Lred[1][tid] + Lred[2][tid] + Lred[3][tid]);
        __syncthreads();

        for (int d = tid; d < EDIM; d += 256) {
            float me = 0.f, ms = 0.f;
#pragma unroll
            for (int k4 = 0; k4 < 4; k4++) {
                float sv = Lsyn[k4][d];
                me += Latt[k4] * sv;
                ms += Latt[4 + k4] * sv;
            }
            Lme[d] = me; Lms[d] = ms;
        }
        __syncthreads();

        float pe = 0.f, ps = 0.f;
        for (int d = tid; d < DE; d += 256) {
            float ve = (d < DDIM) ? Lh[d] : Lme[d - DDIM];
            float vs = (d < DDIM) ? Lh[d] : Lms[d - DDIM];
            pe += ve * w_se[d];
            ps += vs * w_ss[d];
        }
        pe = wave_red(pe); ps = wave_red(ps);
        if (lane == 0) { Lred[wv][0] = pe; Lred[wv][1] = ps; }
        __syncthreads();
        if (tid == 0) {
            float de_ = Lred[0][0] + Lred[1][0] + Lred[2][0] + Lred[3][0];
            float ds_ = Lred[0][1] + Lred[1][1] + Lred[2][1] + Lred[3][1];
            Lco[0] = __expf(tanh_(de_ + b_se[0]));
            Lco[1] = __expf(tanh_(ds_ + b_ss[0]));
        }
        __syncthreads();
        float ce = Lco[0], cs = Lco[1];
#pragma unroll
        for (int cc = 0; cc < 3; cc++) {
            int d = tid + 256 * cc;
            if (d < DE) {
                float ve = (d < DDIM) ? Lh[d] : Lme[d - DDIM];
                float vs = (d < DDIM) ? Lh[d] : Lms[d - DDIM];
                aB[cc] += ce * ve;
                aH[cc] += cs * vs;
            }
        }
        __syncthreads();
    }

#pragma unroll
    for (int cc = 0; cc < 3; cc++) {
        int d = tid + 256 * cc;
        if (d < DE) {
            atomicAdd(&accHat[d], aH[cc]);
            atomicAdd(&accBar[d], aB[cc]);
        }
    }
}

// ---------------------------------------------------------------------------
// Final logits: emotion = H_BAR @ W_eo + b_eo ; sentiment = H_HAT @ W_so + b_so
// ---------------------------------------------------------------------------
__global__ __launch_bounds__(64) void k_final(
    const float* __restrict__ accHat, const float* __restrict__ accBar,
    const float* __restrict__ W_eo, const float* __restrict__ b_eo,
    const float* __restrict__ W_so, const float* __restrict__ b_so,
    float* __restrict__ out)
{
    const int lane = threadIdx.x;
#pragma unroll
    for (int jq = 0; jq < 8; jq++) {
        float pp = 0.f;
        for (int d = lane; d < DE; d += 64) pp += accBar[d] * W_eo[d * 8 + jq];
        pp = wave_red(pp);
        if (lane == 0) out[jq] = pp + b_eo[jq];
    }
    float pp = 0.f;
    for (int d = lane; d < DE; d += 64) pp += accHat[d] * W_so[d];
    pp = wave_red(pp);
    if (lane == 0) out[8] = pp + b_so[0];
}

extern "C" void kernel_launch(void* const* d_in, const int* in_sizes, int n_in,
                              void* d_out, int out_size, void* d_ws, size_t ws_size,
                              hipStream_t stream)
{
    const int*   sent = (const int*)  d_in[0];
    const float* emb  = (const float*)d_in[1];
    const int*   syn  = (const int*)  d_in[2];
    const float* Wf   = (const float*)d_in[3];
    const float* Uf   = (const float*)d_in[4];
    const float* bfv  = (const float*)d_in[5];
    const float* Wb   = (const float*)d_in[6];
    const float* Ub   = (const float*)d_in[7];
    const float* bbv  = (const float*)d_in[8];
    const float* Wpe  = (const float*)d_in[9];
    const float* bpe  = (const float*)d_in[10];
    const float* Wps  = (const float*)d_in[11];
    const float* bps  = (const float*)d_in[12];
    const float* wse  = (const float*)d_in[13];
    const float* bse  = (const float*)d_in[14];
    const float* wss  = (const float*)d_in[15];
    const float* bss  = (const float*)d_in[16];
    const float* Weo  = (const float*)d_in[17];
    const float* beo  = (const float*)d_in[18];
    const float* Wso  = (const float*)d_in[19];
    const float* bso  = (const float*)d_in[20];

    float* ws  = (float*)d_ws;
    float* xpf = ws;
    float* xpb = xpf + (size_t)SEQ * FH;
    float* hsA = xpb + (size_t)SEQ * FH;
    float* oeA = hsA + (size_t)SEQ * DDIM;
    float* osA = oeA + (size_t)SEQ * DDIM;
    float* accHat = osA + (size_t)SEQ * DDIM;
    float* accBar = accHat + DE;

    hipMemsetAsync(accHat, 0, 2 * DE * sizeof(float), stream);

    k_xp  <<<SEQ / 16, 256, 0, stream>>>(sent, emb, Wf, bfv, Wb, bbv, xpf, xpb);
    k_lstm<<<2,        640, 0, stream>>>(Uf, Ub, xpf, xpb, hsA);
    k_out <<<SEQ / 16, 256, 0, stream>>>(hsA, Wpe, bpe, Wps, bps, oeA, osA);
    k_attn<<<SEQ / 8,  256, 0, stream>>>(sent, syn, emb, hsA, oeA, osA,
                                         wse, bse, wss, bss, accHat, accBar);
    k_final<<<1,        64, 0, stream>>>(accHat, accBar, Weo, beo, Wso, bso,
                                         (float*)d_out);
}